// Round 3
// baseline (274.189 us; speedup 1.0000x reference)
//
#include <hip/hip_runtime.h>
#include <hip/hip_bf16.h>

#define VOCAB   128000
#define BATCH   256
#define SEGS    8
#define SEGLEN  (VOCAB / SEGS)   // 16000 floats per segment
#define TPB     256

// Pack (value, index) into a uint64 such that unsigned max() gives
// (greatest value, then smallest index) — preserves first-occurrence ties.
__device__ inline unsigned long long packvi(float v, int idx) {
    unsigned u = __float_as_uint(v);
    u = (u & 0x80000000u) ? ~u : (u | 0x80000000u);  // order-preserving float->uint
    return ((unsigned long long)u << 32) | (unsigned)(~idx);
}

// Stage 1: grid (SEGS, BATCH); each block argmaxes one 16000-element segment.
// Sampled rows: argmax(logits/t - log(noise)) == argmax(softmax(logits/t)/noise)
// (row-wise softmax is monotone). Greedy rows (t==0): argmax(logits), noise
// never read. Partial written unconditionally to ws — no ws init required.
__global__ __launch_bounds__(TPB) void seg_kernel(
    const float* __restrict__ logits,
    const float* __restrict__ temps,
    const float* __restrict__ noise,
    unsigned long long* __restrict__ ws)
{
    const int seg = blockIdx.x;
    const int row = blockIdx.y;
    const int tid = threadIdx.x;

    const float t = temps[row];
    const bool greedy = (t == 0.0f);
    const float invT  = greedy ? 1.0f : (1.0f / t);

    const int base0 = seg * SEGLEN;  // float offset of this segment
    const float4* __restrict__ lg4 = (const float4*)(logits + (size_t)row * VOCAB + base0);
    const float4* __restrict__ nz4 = (const float4*)(noise  + (size_t)row * VOCAB + base0);
    const int nvec = SEGLEN / 4;     // 4000 float4s

    float best = -INFINITY;
    int   bidx = 0x7fffffff;

    if (greedy) {
        for (int v = tid; v < nvec; v += TPB) {
            float4 l = lg4[v];
            int base = base0 + v * 4;
            if (l.x > best) { best = l.x; bidx = base;     }
            if (l.y > best) { best = l.y; bidx = base + 1; }
            if (l.z > best) { best = l.z; bidx = base + 2; }
            if (l.w > best) { best = l.w; bidx = base + 3; }
        }
    } else {
        for (int v = tid; v < nvec; v += TPB) {
            float4 l = lg4[v];
            float4 n = nz4[v];
            int base = base0 + v * 4;
            float vx = l.x * invT - __logf(n.x);
            float vy = l.y * invT - __logf(n.y);
            float vz = l.z * invT - __logf(n.z);
            float vw = l.w * invT - __logf(n.w);
            if (vx > best) { best = vx; bidx = base;     }
            if (vy > best) { best = vy; bidx = base + 1; }
            if (vz > best) { best = vz; bidx = base + 2; }
            if (vw > best) { best = vw; bidx = base + 3; }
        }
    }

    // Wave butterfly reduce (max value, min index on tie)
    #pragma unroll
    for (int off = 32; off > 0; off >>= 1) {
        float ov = __shfl_xor(best, off, 64);
        int   oi = __shfl_xor(bidx, off, 64);
        if (ov > best || (ov == best && oi < bidx)) { best = ov; bidx = oi; }
    }

    // Cross-wave reduce (4 waves)
    __shared__ float sv[TPB / 64];
    __shared__ int   si[TPB / 64];
    const int wave = tid >> 6;
    const int lane = tid & 63;
    if (lane == 0) { sv[wave] = best; si[wave] = bidx; }
    __syncthreads();

    if (tid == 0) {
        float b  = sv[0];
        int   bi = si[0];
        #pragma unroll
        for (int w = 1; w < TPB / 64; ++w) {
            float ov = sv[w]; int oi = si[w];
            if (ov > b || (ov == b && oi < bi)) { b = ov; bi = oi; }
        }
        ws[(size_t)row * SEGS + seg] = packvi(b, bi);
    }
}

// Stage 2: one thread per row reduces its SEGS partials.
__global__ __launch_bounds__(BATCH) void fin_kernel(
    const unsigned long long* __restrict__ ws,
    int* __restrict__ out)
{
    const int r = threadIdx.x;
    unsigned long long m = ws[(size_t)r * SEGS];
    #pragma unroll
    for (int s = 1; s < SEGS; ++s) {
        unsigned long long v = ws[(size_t)r * SEGS + s];
        if (v > m) m = v;
    }
    out[r] = (int)(~(unsigned)(m & 0xffffffffull));
}

extern "C" void kernel_launch(void* const* d_in, const int* in_sizes, int n_in,
                              void* d_out, int out_size, void* d_ws, size_t ws_size,
                              hipStream_t stream) {
    const float* logits = (const float*)d_in[0];
    const float* temps  = (const float*)d_in[1];
    const float* noise  = (const float*)d_in[2];
    int* out = (int*)d_out;
    unsigned long long* ws = (unsigned long long*)d_ws;

    dim3 grid(SEGS, BATCH);
    seg_kernel<<<grid, TPB, 0, stream>>>(logits, temps, noise, ws);
    fin_kernel<<<1, BATCH, 0, stream>>>(ws, out);
}

// Round 6
// 265.425 us; speedup vs baseline: 1.0330x; 1.0330x over previous
//
#include <hip/hip_runtime.h>
#include <hip/hip_bf16.h>

#define VOCAB   128000
#define BATCH   256
#define SEGS    25
#define TPB     256
#define F4_ROW  (VOCAB / 4)          // 32000 float4 per row
#define F4_SEG  (F4_ROW / SEGS)      // 1280 float4 per segment
#define F4_THR  (F4_SEG / TPB)       // 5 float4 per thread (exact)

// Pack (value, index) into a uint64 so unsigned max() == (greater value,
// then smaller index) — preserves first-occurrence tie-breaking.
__device__ inline unsigned long long packvi(float v, int idx) {
    unsigned u = __float_as_uint(v);
    u = (u & 0x80000000u) ? ~u : (u | 0x80000000u);
    return ((unsigned long long)u << 32) | (unsigned)(~idx);
}

// Stage 1: grid (SEGS, BATCH). Deep-MLP variant: each thread issues ALL its
// float4 loads (5 logits + 5 noise) before consuming any, so each wave keeps
// ~10 KB in flight instead of ~2 KB. Sampled rows: argmax(l/t - log(n)) ==
// argmax(softmax(l/t)/n). Greedy rows (t==0) never read noise.
__global__ __launch_bounds__(TPB) void seg_kernel(
    const float* __restrict__ logits,
    const float* __restrict__ temps,
    const float* __restrict__ noise,
    unsigned long long* __restrict__ ws)
{
    const int seg = blockIdx.x;
    const int row = blockIdx.y;
    const int tid = threadIdx.x;

    const float t = temps[row];
    const bool greedy = (t == 0.0f);
    const float invT  = greedy ? 1.0f : (1.0f / t);

    const int segBase = seg * F4_SEG;                 // float4 offset in row
    const float4* __restrict__ lg4 = (const float4*)logits + (size_t)row * F4_ROW + segBase;
    const float4* __restrict__ nz4 = (const float4*)noise  + (size_t)row * F4_ROW + segBase;

    float best = -INFINITY;
    int   bidx = 0x7fffffff;

    if (greedy) {
        float4 L[F4_THR];
        #pragma unroll
        for (int k = 0; k < F4_THR; ++k) L[k] = lg4[tid + k * TPB];
        #pragma unroll
        for (int k = 0; k < F4_THR; ++k) {
            const int base = (segBase + tid + k * TPB) * 4;
            if (L[k].x > best) { best = L[k].x; bidx = base;     }
            if (L[k].y > best) { best = L[k].y; bidx = base + 1; }
            if (L[k].z > best) { best = L[k].z; bidx = base + 2; }
            if (L[k].w > best) { best = L[k].w; bidx = base + 3; }
        }
    } else {
        float4 L[F4_THR], N[F4_THR];
        #pragma unroll
        for (int k = 0; k < F4_THR; ++k) L[k] = lg4[tid + k * TPB];
        #pragma unroll
        for (int k = 0; k < F4_THR; ++k) N[k] = nz4[tid + k * TPB];
        #pragma unroll
        for (int k = 0; k < F4_THR; ++k) {
            const int base = (segBase + tid + k * TPB) * 4;
            const float vx = L[k].x * invT - __logf(N[k].x);
            const float vy = L[k].y * invT - __logf(N[k].y);
            const float vz = L[k].z * invT - __logf(N[k].z);
            const float vw = L[k].w * invT - __logf(N[k].w);
            if (vx > best) { best = vx; bidx = base;     }
            if (vy > best) { best = vy; bidx = base + 1; }
            if (vz > best) { best = vz; bidx = base + 2; }
            if (vw > best) { best = vw; bidx = base + 3; }
        }
    }

    // Wave butterfly reduce (max value, min index on tie)
    #pragma unroll
    for (int off = 32; off > 0; off >>= 1) {
        float ov = __shfl_xor(best, off, 64);
        int   oi = __shfl_xor(bidx, off, 64);
        if (ov > best || (ov == best && oi < bidx)) { best = ov; bidx = oi; }
    }

    // Cross-wave reduce (4 waves)
    __shared__ float sv[TPB / 64];
    __shared__ int   si[TPB / 64];
    const int wave = tid >> 6;
    const int lane = tid & 63;
    if (lane == 0) { sv[wave] = best; si[wave] = bidx; }
    __syncthreads();

    if (tid == 0) {
        float b  = sv[0];
        int   bi = si[0];
        #pragma unroll
        for (int w = 1; w < TPB / 64; ++w) {
            float ov = sv[w]; int oi = si[w];
            if (ov > b || (ov == b && oi < bi)) { b = ov; bi = oi; }
        }
        ws[(size_t)row * SEGS + seg] = packvi(b, bi);
    }
}

// Stage 2: one thread per row reduces its SEGS partials.
__global__ __launch_bounds__(BATCH) void fin_kernel(
    const unsigned long long* __restrict__ ws,
    int* __restrict__ out)
{
    const int r = threadIdx.x;
    unsigned long long m = ws[(size_t)r * SEGS];
    #pragma unroll
    for (int s = 1; s < SEGS; ++s) {
        unsigned long long v = ws[(size_t)r * SEGS + s];
        if (v > m) m = v;
    }
    out[r] = (int)(~(unsigned)(m & 0xffffffffull));
}

extern "C" void kernel_launch(void* const* d_in, const int* in_sizes, int n_in,
                              void* d_out, int out_size, void* d_ws, size_t ws_size,
                              hipStream_t stream) {
    const float* logits = (const float*)d_in[0];
    const float* temps  = (const float*)d_in[1];
    const float* noise  = (const float*)d_in[2];
    int* out = (int*)d_out;
    unsigned long long* ws = (unsigned long long*)d_ws;

    dim3 grid(SEGS, BATCH);
    seg_kernel<<<grid, TPB, 0, stream>>>(logits, temps, noise, ws);
    fin_kernel<<<1, BATCH, 0, stream>>>(ws, out);
}

// Round 7
// 242.175 us; speedup vs baseline: 1.1322x; 1.0960x over previous
//
#include <hip/hip_runtime.h>
#include <hip/hip_bf16.h>

#define VOCAB   128000
#define BATCH   256
#define SEGS    25
#define TPB     256
#define F4_ROW  (VOCAB / 4)          // 32000 float4 per row
#define F4_SEG  (F4_ROW / SEGS)      // 1280 float4 per segment
#define F4_THR  (F4_SEG / TPB)       // 5 float4 per thread (exact)

typedef float f32x4 __attribute__((ext_vector_type(4)));

// Pack (value, index) into a uint64 so unsigned max() == (greater value,
// then smaller index) — preserves first-occurrence tie-breaking.
__device__ inline unsigned long long packvi(float v, int idx) {
    unsigned u = __float_as_uint(v);
    u = (u & 0x80000000u) ? ~u : (u | 0x80000000u);
    return ((unsigned long long)u << 32) | (unsigned)(~idx);
}

// Stage 1: grid (SEGS, BATCH). This round:
//  (a) sched_barrier(0) after the load block — forces ALL 10 float4 loads to
//      issue before any consume (R6 showed the compiler collapsed the batch
//      to ~3 in flight, VGPR=28).
//  (b) non-temporal loads — nt flag stops L3 allocation on miss, so we stop
//      evicting the harness-restore's dirty lines (R6: 207 MB concurrent
//      writeback during the kernel window).
// Sampled rows: argmax(l/t - log(n)) == argmax(softmax(l/t)/n).
// Greedy rows (t==0) never read noise.
__global__ __launch_bounds__(TPB) void seg_kernel(
    const float* __restrict__ logits,
    const float* __restrict__ temps,
    const float* __restrict__ noise,
    unsigned long long* __restrict__ ws)
{
    const int seg = blockIdx.x;
    const int row = blockIdx.y;
    const int tid = threadIdx.x;

    const float t = temps[row];
    const bool greedy = (t == 0.0f);
    const float invT  = greedy ? 1.0f : (1.0f / t);

    const int segBase = seg * F4_SEG;                 // float4 offset in row
    const f32x4* __restrict__ lg4 = (const f32x4*)logits + (size_t)row * F4_ROW + segBase;
    const f32x4* __restrict__ nz4 = (const f32x4*)noise  + (size_t)row * F4_ROW + segBase;

    float best = -INFINITY;
    int   bidx = 0x7fffffff;

    if (greedy) {
        f32x4 L[F4_THR];
        #pragma unroll
        for (int k = 0; k < F4_THR; ++k)
            L[k] = __builtin_nontemporal_load(lg4 + tid + k * TPB);
        __builtin_amdgcn_sched_barrier(0);   // no consume hoisted above loads
        #pragma unroll
        for (int k = 0; k < F4_THR; ++k) {
            const int base = (segBase + tid + k * TPB) * 4;
            if (L[k].x > best) { best = L[k].x; bidx = base;     }
            if (L[k].y > best) { best = L[k].y; bidx = base + 1; }
            if (L[k].z > best) { best = L[k].z; bidx = base + 2; }
            if (L[k].w > best) { best = L[k].w; bidx = base + 3; }
        }
    } else {
        f32x4 L[F4_THR], N[F4_THR];
        #pragma unroll
        for (int k = 0; k < F4_THR; ++k)
            L[k] = __builtin_nontemporal_load(lg4 + tid + k * TPB);
        #pragma unroll
        for (int k = 0; k < F4_THR; ++k)
            N[k] = __builtin_nontemporal_load(nz4 + tid + k * TPB);
        __builtin_amdgcn_sched_barrier(0);   // force all 10 loads in flight
        #pragma unroll
        for (int k = 0; k < F4_THR; ++k) {
            const int base = (segBase + tid + k * TPB) * 4;
            const float vx = L[k].x * invT - __logf(N[k].x);
            const float vy = L[k].y * invT - __logf(N[k].y);
            const float vz = L[k].z * invT - __logf(N[k].z);
            const float vw = L[k].w * invT - __logf(N[k].w);
            if (vx > best) { best = vx; bidx = base;     }
            if (vy > best) { best = vy; bidx = base + 1; }
            if (vz > best) { best = vz; bidx = base + 2; }
            if (vw > best) { best = vw; bidx = base + 3; }
        }
    }

    // Wave butterfly reduce (max value, min index on tie)
    #pragma unroll
    for (int off = 32; off > 0; off >>= 1) {
        float ov = __shfl_xor(best, off, 64);
        int   oi = __shfl_xor(bidx, off, 64);
        if (ov > best || (ov == best && oi < bidx)) { best = ov; bidx = oi; }
    }

    // Cross-wave reduce (4 waves)
    __shared__ float sv[TPB / 64];
    __shared__ int   si[TPB / 64];
    const int wave = tid >> 6;
    const int lane = tid & 63;
    if (lane == 0) { sv[wave] = best; si[wave] = bidx; }
    __syncthreads();

    if (tid == 0) {
        float b  = sv[0];
        int   bi = si[0];
        #pragma unroll
        for (int w = 1; w < TPB / 64; ++w) {
            float ov = sv[w]; int oi = si[w];
            if (ov > b || (ov == b && oi < bi)) { b = ov; bi = oi; }
        }
        ws[(size_t)row * SEGS + seg] = packvi(b, bi);
    }
}

// Stage 2: one thread per row reduces its SEGS partials.
__global__ __launch_bounds__(BATCH) void fin_kernel(
    const unsigned long long* __restrict__ ws,
    int* __restrict__ out)
{
    const int r = threadIdx.x;
    unsigned long long m = ws[(size_t)r * SEGS];
    #pragma unroll
    for (int s = 1; s < SEGS; ++s) {
        unsigned long long v = ws[(size_t)r * SEGS + s];
        if (v > m) m = v;
    }
    out[r] = (int)(~(unsigned)(m & 0xffffffffull));
}

extern "C" void kernel_launch(void* const* d_in, const int* in_sizes, int n_in,
                              void* d_out, int out_size, void* d_ws, size_t ws_size,
                              hipStream_t stream) {
    const float* logits = (const float*)d_in[0];
    const float* temps  = (const float*)d_in[1];
    const float* noise  = (const float*)d_in[2];
    int* out = (int*)d_out;
    unsigned long long* ws = (unsigned long long*)d_ws;

    dim3 grid(SEGS, BATCH);
    seg_kernel<<<grid, TPB, 0, stream>>>(logits, temps, noise, ws);
    fin_kernel<<<1, BATCH, 0, stream>>>(ws, out);
}